// Round 1
// baseline (1688.380 us; speedup 1.0000x reference)
//
#include <hip/hip_runtime.h>
#include <hip/hip_bf16.h>

#define N_TOK 16384
#define HD 1024
#define FD 4096
#define NE 8

typedef __attribute__((ext_vector_type(8))) short short8;
typedef __attribute__((ext_vector_type(4))) float f32x4;

__device__ __forceinline__ unsigned short f2b(float f) {
  union { __hip_bfloat16 h; unsigned short u; } c;
  c.h = __float2bfloat16(f);
  return c.u;
}

__device__ __forceinline__ float gelu_tanh(float x) {
  const float c = 0.7978845608028654f;  // sqrt(2/pi)
  float u = c * (x + 0.044715f * x * x * x);
  float t = 1.0f - 2.0f / (__expf(2.0f * u) + 1.0f);
  return 0.5f * x * (1.0f + t);
}

__device__ __forceinline__ void gload_lds16(const void* g, void* l) {
  __builtin_amdgcn_global_load_lds((const __attribute__((address_space(1))) void*)g,
                                   (__attribute__((address_space(3))) void*)l, 16, 0, 0);
}

// x fp32 -> bf16, 4 elems/thread
__global__ void cvt_x(const float* __restrict__ x, unsigned short* __restrict__ xb) {
  int i = blockIdx.x * 256 + threadIdx.x;
  float4 v = ((const float4*)x)[i];
  ushort4 u;
  u.x = f2b(v.x); u.y = f2b(v.y); u.z = f2b(v.z); u.w = f2b(v.w);
  ((ushort4*)xb)[i] = u;
}

// in [NE][R][C] fp32 -> out [NE][C][R] bf16  (tiled transpose)
__global__ void transpose_cvt(const float* __restrict__ in, unsigned short* __restrict__ out,
                              int R, int C) {
  __shared__ float tile[32][33];
  const size_t mo = (size_t)blockIdx.z * R * C;
  const float* ip = in + mo;
  unsigned short* op = out + mo;
  int c0 = blockIdx.x * 32, r0 = blockIdx.y * 32;
  int tx = threadIdx.x, ty = threadIdx.y;
#pragma unroll
  for (int j = 0; j < 4; j++)
    tile[ty + j * 8][tx] = ip[(size_t)(r0 + ty + j * 8) * C + (c0 + tx)];
  __syncthreads();
#pragma unroll
  for (int j = 0; j < 4; j++)
    op[(size_t)(c0 + ty + j * 8) * R + (r0 + tx)] = f2b(tile[tx][ty + j * 8]);
}

// one wave per token: fp32 logits, top-2, softmax, compact routing lists
__global__ void router(const float* __restrict__ x, const float* __restrict__ wg,
                       int* __restrict__ counts, int* __restrict__ tok_idx,
                       float* __restrict__ tok_w) {
  int wid = threadIdx.x >> 6;
  int lane = threadIdx.x & 63;
  int t = blockIdx.x * 4 + wid;
  const float* xr = x + (size_t)t * HD;
  float acc[NE];
#pragma unroll
  for (int e = 0; e < NE; e++) acc[e] = 0.0f;
  for (int i = lane; i < HD; i += 64) {
    float xv = xr[i];
    const float* wr = wg + i * NE;
#pragma unroll
    for (int e = 0; e < NE; e++) acc[e] += xv * wr[e];
  }
#pragma unroll
  for (int e = 0; e < NE; e++) {
    for (int off = 32; off > 0; off >>= 1) acc[e] += __shfl_down(acc[e], off);
  }
  if (lane == 0) {
    int i0 = 0; float v0 = acc[0];
#pragma unroll
    for (int e = 1; e < NE; e++) { if (acc[e] > v0) { v0 = acc[e]; i0 = e; } }
    int i1 = -1; float v1 = -1e30f;
#pragma unroll
    for (int e = 0; e < NE; e++) { if (e != i0 && acc[e] > v1) { v1 = acc[e]; i1 = e; } }
    float w0 = 1.0f / (1.0f + __expf(v1 - v0));
    float w1 = 1.0f - w0;
    int s0 = atomicAdd(&counts[i0], 1);
    tok_idx[i0 * N_TOK + s0] = t; tok_w[i0 * N_TOK + s0] = w0;
    int s1 = atomicAdd(&counts[i1], 1);
    tok_idx[i1 * N_TOK + s1] = t; tok_w[i1 * N_TOK + s1] = w1;
  }
}

__global__ void scan_counts(const int* __restrict__ counts, int* __restrict__ offsets) {
  int s = 0;
  for (int e = 0; e < NE; e++) { offsets[e] = s; s += counts[e]; }
  offsets[NE] = s;
}

// 128x128 block tile, BK=32, 4 waves of 4x4 16x16x32 bf16 MFMA (m97 pattern).
// IS_G1: A = gathered xb rows [*,KD=H], Bt = W1^T [NE][FD][HD], out -> hdd (gelu, bf16)
// else : A = hdd rows          [*,KD=F], Bt = W2^T [NE][HD][FD], out -> atomicAdd fp32
template <bool IS_G1, int KD, int ND>
__global__ __launch_bounds__(256) void moe_gemm(
    const unsigned short* __restrict__ A, const unsigned short* __restrict__ Bt,
    const float* __restrict__ bias, const int* __restrict__ counts,
    const int* __restrict__ offsets, const int* __restrict__ tok_idx,
    const float* __restrict__ tok_w, unsigned short* __restrict__ hdd,
    float* __restrict__ out) {
  const int e = blockIdx.z;
  const int cnt = counts[e];
  const int m0 = blockIdx.y * 128;
  if (m0 >= cnt) return;
  const int n0 = blockIdx.x * 128;
  const int offs = offsets[e];

  __shared__ unsigned short lA[128 * 32];
  __shared__ unsigned short lB[128 * 32];

  const int tid = threadIdx.x;
  const int r0 = tid >> 2, r1 = 64 + (tid >> 2);
  const int ck = (tid & 3) * 8;  // element offset of this thread's 16B chunk

  const unsigned short *aB0, *aB1;
  if constexpr (IS_G1) {
    const int* tl = tok_idx + e * N_TOK;
    int t0 = tl[min(m0 + r0, cnt - 1)];
    int t1 = tl[min(m0 + r1, cnt - 1)];
    aB0 = A + (size_t)t0 * KD + ck;
    aB1 = A + (size_t)t1 * KD + ck;
  } else {
    aB0 = A + (size_t)(offs + m0 + r0) * KD + ck;
    aB1 = A + (size_t)(offs + m0 + r1) * KD + ck;
  }
  const unsigned short* bBase = Bt + (size_t)e * ND * KD;
  const unsigned short* bB0 = bBase + (size_t)(n0 + r0) * KD + ck;
  const unsigned short* bB1 = bBase + (size_t)(n0 + r1) * KD + ck;

  const int lane = tid & 63;
  const int wid = tid >> 6;
  const int wm = (wid >> 1) * 64, wn = (wid & 1) * 64;
  const int lrow = lane & 15, lkg = lane >> 4;

  f32x4 acc[4][4] = {};

  for (int k0 = 0; k0 < KD; k0 += 32) {
    gload_lds16(aB0 + k0, &lA[tid * 8]);
    gload_lds16(aB1 + k0, &lA[2048 + tid * 8]);
    gload_lds16(bB0 + k0, &lB[tid * 8]);
    gload_lds16(bB1 + k0, &lB[2048 + tid * 8]);
    __syncthreads();
    short8 af[4], bf[4];
#pragma unroll
    for (int i = 0; i < 4; i++)
      af[i] = *(const short8*)&lA[(wm + i * 16 + lrow) * 32 + lkg * 8];
#pragma unroll
    for (int i = 0; i < 4; i++)
      bf[i] = *(const short8*)&lB[(wn + i * 16 + lrow) * 32 + lkg * 8];
#pragma unroll
    for (int mi = 0; mi < 4; mi++)
#pragma unroll
      for (int ni = 0; ni < 4; ni++)
        acc[mi][ni] = __builtin_amdgcn_mfma_f32_16x16x32_bf16(af[mi], bf[ni], acc[mi][ni], 0, 0, 0);
    __syncthreads();
  }

  // epilogue: D elem (row = lkg*4 + r, col = lrow) within each 16x16 tile
  if constexpr (IS_G1) {
#pragma unroll
    for (int mi = 0; mi < 4; mi++) {
      int mbase = m0 + wm + mi * 16 + lkg * 4;
#pragma unroll
      for (int r = 0; r < 4; r++) {
        int m = mbase + r;
        if (m < cnt) {
          __hip_bfloat16* hrow = (__hip_bfloat16*)(hdd + (size_t)(offs + m) * FD);
#pragma unroll
          for (int ni = 0; ni < 4; ni++) {
            int n = n0 + wn + ni * 16 + lrow;
            float v = acc[mi][ni][r] + bias[e * ND + n];
            hrow[n] = __float2bfloat16(gelu_tanh(v));
          }
        }
      }
    }
  } else {
    const int* tl = tok_idx + e * N_TOK;
    const float* wl = tok_w + e * N_TOK;
#pragma unroll
    for (int mi = 0; mi < 4; mi++) {
      int mbase = m0 + wm + mi * 16 + lkg * 4;
#pragma unroll
      for (int r = 0; r < 4; r++) {
        int m = mbase + r;
        if (m < cnt) {
          int t = tl[m];
          float w = wl[m];
          float* orow = out + (size_t)t * HD;
#pragma unroll
          for (int ni = 0; ni < 4; ni++) {
            int n = n0 + wn + ni * 16 + lrow;
            float v = acc[mi][ni][r] + bias[e * ND + n];
            atomicAdd(&orow[n], w * v);
          }
        }
      }
    }
  }
}

// ws layout (bytes):
//   counts   @ 0         (32)
//   offsets  @ 64        (36)
//   tok_idx  @ 256       (8*16384*4 = 524288)
//   tok_w    @ 524544    (524288)
//   xb bf16  @ 1048832   (16384*1024*2 = 33554432)
//   w1t bf16 @ 34603264  (8*4096*1024*2 = 67108864)   [E][F][H]
//   w2t bf16 @ 101712128 (67108864)                   [E][H][F]
//   hdd bf16 @ 168820992 ((32768+128)*4096*2 = 269484032)
// total ~438 MB
extern "C" void kernel_launch(void* const* d_in, const int* in_sizes, int n_in,
                              void* d_out, int out_size, void* d_ws, size_t ws_size,
                              hipStream_t stream) {
  const float* x  = (const float*)d_in[0];
  const float* Wg = (const float*)d_in[1];
  const float* W1 = (const float*)d_in[2];
  const float* b1 = (const float*)d_in[3];
  const float* W2 = (const float*)d_in[4];
  const float* b2 = (const float*)d_in[5];
  float* out = (float*)d_out;

  char* ws = (char*)d_ws;
  int* counts       = (int*)(ws + 0);
  int* offsets      = (int*)(ws + 64);
  int* tok_idx      = (int*)(ws + 256);
  float* tok_w      = (float*)(ws + 524544);
  unsigned short* xb  = (unsigned short*)(ws + 1048832);
  unsigned short* w1t = (unsigned short*)(ws + 34603264);
  unsigned short* w2t = (unsigned short*)(ws + 101712128);
  unsigned short* hdd = (unsigned short*)(ws + 168820992);

  hipMemsetAsync(counts, 0, 64, stream);
  hipMemsetAsync(d_out, 0, (size_t)N_TOK * HD * sizeof(float), stream);

  cvt_x<<<(N_TOK * HD / 4) / 256, 256, 0, stream>>>(x, xb);
  transpose_cvt<<<dim3(FD / 32, HD / 32, NE), dim3(32, 8), 0, stream>>>(W1, w1t, HD, FD);
  transpose_cvt<<<dim3(HD / 32, FD / 32, NE), dim3(32, 8), 0, stream>>>(W2, w2t, FD, HD);
  router<<<N_TOK / 4, 256, 0, stream>>>(x, Wg, counts, tok_idx, tok_w);
  scan_counts<<<1, 1, 0, stream>>>(counts, offsets);

  moe_gemm<true, HD, FD><<<dim3(FD / 128, N_TOK / 128, NE), 256, 0, stream>>>(
      xb, w1t, b1, counts, offsets, tok_idx, tok_w, hdd, out);
  moe_gemm<false, FD, HD><<<dim3(HD / 128, N_TOK / 128, NE), 256, 0, stream>>>(
      hdd, w2t, b2, counts, offsets, tok_idx, tok_w, hdd, out);
}

// Round 2
// 1583.324 us; speedup vs baseline: 1.0664x; 1.0664x over previous
//
#include <hip/hip_runtime.h>
#include <hip/hip_bf16.h>

#define N_TOK 16384
#define HD 1024
#define FD 4096
#define NE 8

typedef __attribute__((ext_vector_type(8))) short short8;
typedef __attribute__((ext_vector_type(4))) float f32x4;

__device__ __forceinline__ unsigned short f2b(float f) {
  union { __hip_bfloat16 h; unsigned short u; } c;
  c.h = __float2bfloat16(f);
  return c.u;
}

__device__ __forceinline__ float b2f(unsigned short u) {
  union { float f; unsigned int i; } c;
  c.i = ((unsigned int)u) << 16;
  return c.f;
}

__device__ __forceinline__ float gelu_tanh(float x) {
  const float c = 0.7978845608028654f;  // sqrt(2/pi)
  float u = c * (x + 0.044715f * x * x * x);
  float t = 1.0f - 2.0f / (__expf(2.0f * u) + 1.0f);
  return 0.5f * x * (1.0f + t);
}

__device__ __forceinline__ void gload_lds16(const void* g, void* l) {
  __builtin_amdgcn_global_load_lds((const __attribute__((address_space(1))) void*)g,
                                   (__attribute__((address_space(3))) void*)l, 16, 0, 0);
}

// x fp32 -> bf16, 4 elems/thread
__global__ void cvt_x(const float* __restrict__ x, unsigned short* __restrict__ xb) {
  int i = blockIdx.x * 256 + threadIdx.x;
  float4 v = ((const float4*)x)[i];
  ushort4 u;
  u.x = f2b(v.x); u.y = f2b(v.y); u.z = f2b(v.z); u.w = f2b(v.w);
  ((ushort4*)xb)[i] = u;
}

// in [NE][R][C] fp32 -> out [NE][C][R] bf16  (tiled transpose)
__global__ void transpose_cvt(const float* __restrict__ in, unsigned short* __restrict__ out,
                              int R, int C) {
  __shared__ float tile[32][33];
  const size_t mo = (size_t)blockIdx.z * R * C;
  const float* ip = in + mo;
  unsigned short* op = out + mo;
  int c0 = blockIdx.x * 32, r0 = blockIdx.y * 32;
  int tx = threadIdx.x, ty = threadIdx.y;
#pragma unroll
  for (int j = 0; j < 4; j++)
    tile[ty + j * 8][tx] = ip[(size_t)(r0 + ty + j * 8) * C + (c0 + tx)];
  __syncthreads();
#pragma unroll
  for (int j = 0; j < 4; j++)
    op[(size_t)(c0 + ty + j * 8) * R + (r0 + tx)] = f2b(tile[tx][ty + j * 8]);
}

// one wave per token: fp32 logits, top-2, softmax, compact routing lists + inverse map
__global__ void router(const float* __restrict__ x, const float* __restrict__ wg,
                       int* __restrict__ counts, int* __restrict__ tok_idx,
                       float* __restrict__ tok_w, int* __restrict__ inv_es,
                       float* __restrict__ inv_w) {
  int wid = threadIdx.x >> 6;
  int lane = threadIdx.x & 63;
  int t = blockIdx.x * 4 + wid;
  const float* xr = x + (size_t)t * HD;
  float acc[NE];
#pragma unroll
  for (int e = 0; e < NE; e++) acc[e] = 0.0f;
  for (int i = lane; i < HD; i += 64) {
    float xv = xr[i];
    const float* wr = wg + i * NE;
#pragma unroll
    for (int e = 0; e < NE; e++) acc[e] += xv * wr[e];
  }
#pragma unroll
  for (int e = 0; e < NE; e++) {
    for (int off = 32; off > 0; off >>= 1) acc[e] += __shfl_down(acc[e], off);
  }
  if (lane == 0) {
    int i0 = 0; float v0 = acc[0];
#pragma unroll
    for (int e = 1; e < NE; e++) { if (acc[e] > v0) { v0 = acc[e]; i0 = e; } }
    int i1 = -1; float v1 = -1e30f;
#pragma unroll
    for (int e = 0; e < NE; e++) { if (e != i0 && acc[e] > v1) { v1 = acc[e]; i1 = e; } }
    float w0 = 1.0f / (1.0f + __expf(v1 - v0));
    float w1 = 1.0f - w0;
    int s0 = atomicAdd(&counts[i0], 1);
    tok_idx[i0 * N_TOK + s0] = t; tok_w[i0 * N_TOK + s0] = w0;
    int s1 = atomicAdd(&counts[i1], 1);
    tok_idx[i1 * N_TOK + s1] = t; tok_w[i1 * N_TOK + s1] = w1;
    inv_es[2 * t + 0] = (i0 << 16) | s0;  inv_w[2 * t + 0] = w0;
    inv_es[2 * t + 1] = (i1 << 16) | s1;  inv_w[2 * t + 1] = w1;
  }
}

__global__ void scan_counts(const int* __restrict__ counts, int* __restrict__ offsets) {
  int s = 0;
  for (int e = 0; e < NE; e++) { offsets[e] = s; s += counts[e]; }
  offsets[NE] = s;
}

// 128x128 block tile, BK=32, 4 waves of 4x4 16x16x32 bf16 MFMA (m97 pattern)
// + XOR bank-conflict swizzle on the LDS chunk index.
// IS_G1: A = gathered xb rows [*,KD=H], Bt = W1^T [NE][FD][HD], out -> hdd (gelu, bf16)
// else : A = hdd rows          [*,KD=F], Bt = W2^T [NE][HD][FD], out -> y (bf16, compact)
template <bool IS_G1, int KD, int ND>
__global__ __launch_bounds__(256) void moe_gemm(
    const unsigned short* __restrict__ A, const unsigned short* __restrict__ Bt,
    const float* __restrict__ bias, const int* __restrict__ counts,
    const int* __restrict__ offsets, const int* __restrict__ tok_idx,
    unsigned short* __restrict__ hdd, unsigned short* __restrict__ y) {
  const int e = blockIdx.z;
  const int cnt = counts[e];
  const int m0 = blockIdx.y * 128;
  if (m0 >= cnt) return;
  const int n0 = blockIdx.x * 128;
  const int offs = offsets[e];

  __shared__ unsigned short lA[128 * 32];
  __shared__ unsigned short lB[128 * 32];

  const int tid = threadIdx.x;
  const int r0 = tid >> 2, r1 = 64 + (tid >> 2);
  // staging swizzle: lane (row, chunk) fetches global chunk (chunk ^ (row>>1)&3).
  // LDS slot (row,c) then holds global chunk c ^ s(row); read side XORs back.
  const int cks = (((tid & 3) ^ ((tid >> 3) & 3))) * 8;  // element offset of 16B chunk

  const unsigned short *aB0, *aB1;
  if constexpr (IS_G1) {
    const int* tl = tok_idx + e * N_TOK;
    int t0 = tl[min(m0 + r0, cnt - 1)];
    int t1 = tl[min(m0 + r1, cnt - 1)];
    aB0 = A + (size_t)t0 * KD + cks;
    aB1 = A + (size_t)t1 * KD + cks;
  } else {
    aB0 = A + (size_t)(offs + m0 + r0) * KD + cks;
    aB1 = A + (size_t)(offs + m0 + r1) * KD + cks;
  }
  const unsigned short* bBase = Bt + (size_t)e * ND * KD;
  const unsigned short* bB0 = bBase + (size_t)(n0 + r0) * KD + cks;
  const unsigned short* bB1 = bBase + (size_t)(n0 + r1) * KD + cks;

  const int lane = tid & 63;
  const int wid = tid >> 6;
  const int wm = (wid >> 1) * 64, wn = (wid & 1) * 64;
  const int lrow = lane & 15, lkg = lane >> 4;
  const int rdk = (lkg ^ ((lrow >> 1) & 3)) * 8;  // read-side XOR (loop-invariant)

  f32x4 acc[4][4] = {};

  for (int k0 = 0; k0 < KD; k0 += 32) {
    gload_lds16(aB0 + k0, &lA[tid * 8]);
    gload_lds16(aB1 + k0, &lA[2048 + tid * 8]);
    gload_lds16(bB0 + k0, &lB[tid * 8]);
    gload_lds16(bB1 + k0, &lB[2048 + tid * 8]);
    __syncthreads();
    short8 af[4], bf[4];
#pragma unroll
    for (int i = 0; i < 4; i++)
      af[i] = *(const short8*)&lA[(wm + i * 16 + lrow) * 32 + rdk];
#pragma unroll
    for (int i = 0; i < 4; i++)
      bf[i] = *(const short8*)&lB[(wn + i * 16 + lrow) * 32 + rdk];
#pragma unroll
    for (int mi = 0; mi < 4; mi++)
#pragma unroll
      for (int ni = 0; ni < 4; ni++)
        acc[mi][ni] = __builtin_amdgcn_mfma_f32_16x16x32_bf16(af[mi], bf[ni], acc[mi][ni], 0, 0, 0);
    __syncthreads();
  }

  // epilogue: D elem (row = lkg*4 + r, col = lrow) within each 16x16 tile
#pragma unroll
  for (int mi = 0; mi < 4; mi++) {
    int mbase = m0 + wm + mi * 16 + lkg * 4;
#pragma unroll
    for (int r = 0; r < 4; r++) {
      int m = mbase + r;
      if (m < cnt) {
        if constexpr (IS_G1) {
          __hip_bfloat16* hrow = (__hip_bfloat16*)(hdd + (size_t)(offs + m) * FD);
#pragma unroll
          for (int ni = 0; ni < 4; ni++) {
            int n = n0 + wn + ni * 16 + lrow;
            float v = acc[mi][ni][r] + bias[e * ND + n];
            hrow[n] = __float2bfloat16(gelu_tanh(v));
          }
        } else {
          __hip_bfloat16* yrow = (__hip_bfloat16*)(y + (size_t)(offs + m) * HD);
#pragma unroll
          for (int ni = 0; ni < 4; ni++) {
            int n = n0 + wn + ni * 16 + lrow;
            float v = acc[mi][ni][r] + bias[e * ND + n];
            yrow[n] = __float2bfloat16(v);
          }
        }
      }
    }
  }
}

// per-token gather of its 2 expert rows, weighted combine -> fp32 out
__global__ void combine(const unsigned short* __restrict__ y, const int* __restrict__ offsets,
                        const int* __restrict__ inv_es, const float* __restrict__ inv_w,
                        float* __restrict__ out) {
  int t = blockIdx.x;
  int p0 = inv_es[2 * t], p1 = inv_es[2 * t + 1];
  float w0 = inv_w[2 * t], w1 = inv_w[2 * t + 1];
  int g0 = offsets[p0 >> 16] + (p0 & 0xffff);
  int g1 = offsets[p1 >> 16] + (p1 & 0xffff);
  const ushort4* ra = (const ushort4*)(y + (size_t)g0 * HD);
  const ushort4* rb = (const ushort4*)(y + (size_t)g1 * HD);
  int i = threadIdx.x;
  ushort4 a = ra[i], b = rb[i];
  float4 o;
  o.x = w0 * b2f(a.x) + w1 * b2f(b.x);
  o.y = w0 * b2f(a.y) + w1 * b2f(b.y);
  o.z = w0 * b2f(a.z) + w1 * b2f(b.z);
  o.w = w0 * b2f(a.w) + w1 * b2f(b.w);
  ((float4*)(out + (size_t)t * HD))[i] = o;
}

// ws layout (bytes):
//   counts   @ 0          (32)
//   offsets  @ 64         (36)
//   tok_idx  @ 256        (524288)
//   tok_w    @ 524544     (524288)
//   inv_es   @ 1048832    (131072)
//   inv_w    @ 1179904    (131072)
//   xb bf16  @ 1310976    (33554432)
//   w1t bf16 @ 34865408   (67108864)  [E][F][H] — dead after GEMM1; y aliases here
//   y   bf16 @ 34865408   (67108864)  [32768][H]
//   w2t bf16 @ 101974272  (67108864)  [E][H][F]
//   hdd bf16 @ 169083136  ((32768+128)*4096*2 = 269484032)
// total ~438 MB (same as round 1, which fit)
extern "C" void kernel_launch(void* const* d_in, const int* in_sizes, int n_in,
                              void* d_out, int out_size, void* d_ws, size_t ws_size,
                              hipStream_t stream) {
  const float* x  = (const float*)d_in[0];
  const float* Wg = (const float*)d_in[1];
  const float* W1 = (const float*)d_in[2];
  const float* b1 = (const float*)d_in[3];
  const float* W2 = (const float*)d_in[4];
  const float* b2 = (const float*)d_in[5];
  float* out = (float*)d_out;

  char* ws = (char*)d_ws;
  int* counts       = (int*)(ws + 0);
  int* offsets      = (int*)(ws + 64);
  int* tok_idx      = (int*)(ws + 256);
  float* tok_w      = (float*)(ws + 524544);
  int* inv_es       = (int*)(ws + 1048832);
  float* inv_w      = (float*)(ws + 1179904);
  unsigned short* xb  = (unsigned short*)(ws + 1310976);
  unsigned short* w1t = (unsigned short*)(ws + 34865408);
  unsigned short* yb  = (unsigned short*)(ws + 34865408);  // aliases w1t (dead after GEMM1)
  unsigned short* w2t = (unsigned short*)(ws + 101974272);
  unsigned short* hdd = (unsigned short*)(ws + 169083136);

  hipMemsetAsync(counts, 0, 64, stream);

  cvt_x<<<(N_TOK * HD / 4) / 256, 256, 0, stream>>>(x, xb);
  transpose_cvt<<<dim3(FD / 32, HD / 32, NE), dim3(32, 8), 0, stream>>>(W1, w1t, HD, FD);
  transpose_cvt<<<dim3(HD / 32, FD / 32, NE), dim3(32, 8), 0, stream>>>(W2, w2t, FD, HD);
  router<<<N_TOK / 4, 256, 0, stream>>>(x, Wg, counts, tok_idx, tok_w, inv_es, inv_w);
  scan_counts<<<1, 1, 0, stream>>>(counts, offsets);

  moe_gemm<true, HD, FD><<<dim3(FD / 128, N_TOK / 128, NE), 256, 0, stream>>>(
      xb, w1t, b1, counts, offsets, tok_idx, hdd, yb);
  moe_gemm<false, FD, HD><<<dim3(HD / 128, N_TOK / 128, NE), 256, 0, stream>>>(
      hdd, w2t, b2, counts, offsets, tok_idx, hdd, yb);
  combine<<<N_TOK, 256, 0, stream>>>(yb, offsets, inv_es, inv_w, out);
}